// Round 6
// baseline (321.741 us; speedup 1.0000x reference)
//
#include <hip/hip_runtime.h>
#include <hip/hip_bf16.h>

// GatedConv: N=50000, E=800000, D=128, G=64, 2 layers.
// Round 15: keep round-14 layer/pool kernels (proven). Fuse the three
// independent setup kernels (edge scatter, embed gather, weight pack) into
// ONE dispatch via block-range split so they overlap on different CUs:
// scatter is memory-RMW-bound at 47us with VALUBusy 0.5% -- gather+pack
// ride along for free. deg is zeroed by hipMemsetAsync (capture-safe
// memset node) to preserve ordering. Scatter reads edges via int4
// (4 edges/thread, 782 blocks -> fully co-resident with gather blocks).
// Dispatches: memset + setup + 2x(aggregate+gru) + pool = 7.

#define DTHREADS 256
#define CAP 64

typedef __attribute__((ext_vector_type(8))) short bf16x8;
typedef __attribute__((ext_vector_type(4))) float f32x4;

__device__ __forceinline__ float sigf(float x) { return 1.0f / (1.0f + __expf(-x)); }
__device__ __forceinline__ float tanhfast(float x) { return 1.0f - 2.0f / (1.0f + __expf(2.0f * x)); }

__device__ __forceinline__ unsigned short f2bf_rne(float x) {
  unsigned int u = __float_as_uint(x);
  u += 0x7fff + ((u >> 16) & 1);
  return (unsigned short)(u >> 16);
}
__device__ __forceinline__ float bf2f(unsigned int lo16) {
  return __uint_as_float(lo16 << 16);
}

// ---- fused setup: [scatter blocks | gather blocks | pack blocks] ---------
__global__ __launch_bounds__(DTHREADS) void setup_kernel(
    const int* __restrict__ e_src, const int* __restrict__ e_dst,
    int* __restrict__ deg, int* __restrict__ csr, int E, int nS,
    const float* __restrict__ embed, const int* __restrict__ node_ids,
    unsigned short* __restrict__ hb, int N, int nG,
    const float* __restrict__ w_hh, const float* __restrict__ conv_w,
    const float* __restrict__ w_ih, unsigned short* __restrict__ wpk_hh,
    unsigned short* __restrict__ wpk_wc, int nl) {
  int b = blockIdx.x;
  if (b < nS) {
    // ---- edge scatter: 4 edges/thread, int4 coalesced reads ----
    int base = (b * DTHREADS + threadIdx.x) * 4;
    if (base + 3 < E) {
      int4 d4 = *(const int4*)&e_dst[base];
      int4 s4 = *(const int4*)&e_src[base];
      int slot;
      slot = atomicAdd(&deg[d4.x], 1);
      if (slot < CAP) csr[(size_t)d4.x * CAP + slot] = s4.x;
      slot = atomicAdd(&deg[d4.y], 1);
      if (slot < CAP) csr[(size_t)d4.y * CAP + slot] = s4.y;
      slot = atomicAdd(&deg[d4.z], 1);
      if (slot < CAP) csr[(size_t)d4.z * CAP + slot] = s4.z;
      slot = atomicAdd(&deg[d4.w], 1);
      if (slot < CAP) csr[(size_t)d4.w * CAP + slot] = s4.w;
    } else {
      for (int q = 0; q < 4; ++q) {
        int e = base + q;
        if (e < E) {
          int d = e_dst[e];
          int slot = atomicAdd(&deg[d], 1);
          if (slot < CAP) csr[(size_t)d * CAP + slot] = e_src[e];
        }
      }
    }
    return;
  }
  b -= nS;
  if (b < nG) {
    // ---- embed gather: 32 threads/node, float4 -> ushort4 ----
    int idx = b * DTHREADS + threadIdx.x;
    if (idx >= N * 32) return;
    int n = idx >> 5;
    int c = (idx & 31) * 4;
    int v = node_ids[n];
    float4 val = *(const float4*)&embed[(size_t)v * 128 + c];
    unsigned short bb[4] = {f2bf_rne(val.x), f2bf_rne(val.y), f2bf_rne(val.z), f2bf_rne(val.w)};
    *(ushort4*)&hb[(size_t)n * 128 + c] = *(ushort4*)bb;
    return;
  }
  b -= nG;
  // ---- weight pack (wpk_hh, wpk_wc = conv_w @ w_ih fused) ----
  int id = b * DTHREADS + threadIdx.x;
  int seg = id / (384 * 128);
  if (seg > nl) return;
  int r = id - seg * (384 * 128);
  int f = r >> 3, i = r & 7;
  int l = f & 63;
  int s = (f >> 6) & 3;
  int t = (f >> 8) & 3;
  int jb = f >> 10;
  int j = jb * 64 + t * 16 + (l & 15);
  int k = s * 32 + (l >> 4) * 8 + i;
  float val;
  unsigned short* dst;
  if (seg == 0) {
    val = w_hh[j * 128 + k];
    dst = wpk_hh;
  } else {
    const float* conv = conv_w + (size_t)(seg - 1) * 128 * 128;
    float acc = 0.f;
    for (int d = 0; d < 128; d += 4) {
      float4 cv = *(const float4*)&conv[k * 128 + d];
      float4 wv = *(const float4*)&w_ih[j * 128 + d];
      acc += cv.x * wv.x + cv.y * wv.y + cv.z * wv.z + cv.w * wv.w;
    }
    val = acc;
    dst = wpk_wc + (size_t)(seg - 1) * 384 * 128;
  }
  dst[(size_t)f * 8 + i] = f2bf_rne(val);
}

// ---- aggregate: quarter-wave (16 lanes) per node, 16 edges in flight -----
__global__ __launch_bounds__(DTHREADS) void aggregate_kernel(
    const unsigned short* __restrict__ hb, const int* __restrict__ deg,
    const int* __restrict__ csr, unsigned short* __restrict__ agg, int N) {
  int node = (blockIdx.x * DTHREADS + threadIdx.x) >> 4;
  if (node >= N) return;
  int c = threadIdx.x & 15;
  int e = min(deg[node], CAP);
  const int* cs = csr + (size_t)node * CAP;
  float acc[8] = {0.f, 0.f, 0.f, 0.f, 0.f, 0.f, 0.f, 0.f};
  for (int i = 0; i < e; i += 16) {
    int idx[16];
    #pragma unroll
    for (int q = 0; q < 16; ++q) {
      int ii = i + q;
      idx[q] = cs[ii < e ? ii : 0];
    }
    uint4 d[16];
    #pragma unroll
    for (int q = 0; q < 16; ++q)
      d[q] = *(const uint4*)&hb[(size_t)idx[q] * 128 + c * 8];
    #pragma unroll
    for (int q = 0; q < 16; ++q) {
      if (i + q < e) {
        const unsigned int* dp = (const unsigned int*)&d[q];
        #pragma unroll
        for (int u = 0; u < 4; ++u) {
          acc[2 * u]     += bf2f(dp[u] & 0xffffu);
          acc[2 * u + 1] += bf2f(dp[u] >> 16);
        }
      }
    }
  }
  unsigned int o[4];
  #pragma unroll
  for (int q = 0; q < 4; ++q)
    o[q] = (unsigned int)f2bf_rne(acc[2 * q]) | ((unsigned int)f2bf_rne(acc[2 * q + 1]) << 16);
  *(uint4*)&agg[(size_t)node * 128 + c * 8] = *(uint4*)o;
}

// ---- persistent fused GRU (weights in VGPRs, register prefetch) ----------
__global__ __launch_bounds__(512, 2) void fused_gru_kernel(
    const unsigned short* __restrict__ aggb, const unsigned short* __restrict__ wpk_wc,
    const unsigned short* __restrict__ wpk_hh, const float* __restrict__ b_ih,
    const float* __restrict__ b_hh, unsigned short* __restrict__ hb,
    int N, int nchunks) {
  __shared__ __align__(16) unsigned short Ag[32 * 128];  // 8 KB
  __shared__ __align__(16) unsigned short Hs[32 * 128];  // 8 KB
  const int tid = threadIdx.x;
  const int wv = tid >> 6, lane = tid & 63;
  const int lm = lane & 15, quad = lane >> 4;

  bf16x8 BI[3][4], BH[3][4];
  #pragma unroll
  for (int g = 0; g < 3; ++g) {
    int jb = g * 2 + (wv >> 2);
    int t = wv & 3;
    #pragma unroll
    for (int s = 0; s < 4; ++s) {
      size_t f = ((size_t)(jb * 4 + t) * 4 + s) * 64 + lane;
      BI[g][s] = *(const bf16x8*)&wpk_wc[f * 8];
      BH[g][s] = *(const bf16x8*)&wpk_hh[f * 8];
    }
  }

  const int jc = wv * 16 + lm;
  const float bir = b_ih[jc], biz = b_ih[128 + jc], bin_ = b_ih[256 + jc];
  const float bhr = b_hh[jc], bhz = b_hh[128 + jc], bhn = b_hh[256 + jc];
  const int c0 = jc >> 3, ej = jc & 7;

  const int srow = tid >> 4, scol = tid & 15;
  const int sdc = (scol ^ (srow & 15)) * 8;

  int ci = blockIdx.x;
  uint4 va = make_uint4(0, 0, 0, 0), vh = make_uint4(0, 0, 0, 0);
  if (ci < nchunks) {
    int n = ci * 32 + srow;
    if (n < N) {
      va = *(const uint4*)&aggb[(size_t)n * 128 + scol * 8];
      vh = *(const uint4*)&hb[(size_t)n * 128 + scol * 8];
    }
  }

  for (; ci < nchunks; ci += gridDim.x) {
    *(uint4*)&Ag[srow * 128 + sdc] = va;
    *(uint4*)&Hs[srow * 128 + sdc] = vh;
    __syncthreads();

    int cn = ci + gridDim.x;
    va = make_uint4(0, 0, 0, 0); vh = make_uint4(0, 0, 0, 0);
    if (cn < nchunks) {
      int n = cn * 32 + srow;
      if (n < N) {
        va = *(const uint4*)&aggb[(size_t)n * 128 + scol * 8];
        vh = *(const uint4*)&hb[(size_t)n * 128 + scol * 8];
      }
    }

    f32x4 accI[2][3], accH[2][3];
    #pragma unroll
    for (int mi = 0; mi < 2; ++mi)
      #pragma unroll
      for (int g = 0; g < 3; ++g) {
        accI[mi][g] = (f32x4){0.f, 0.f, 0.f, 0.f};
        accH[mi][g] = (f32x4){0.f, 0.f, 0.f, 0.f};
      }

    #pragma unroll
    for (int s = 0; s < 4; ++s) {
      bf16x8 afA[2], afH[2];
      #pragma unroll
      for (int mi = 0; mi < 2; ++mi) {
        int m = mi * 16 + lm;
        int chunk = (s * 4 + quad) ^ (m & 15);
        afA[mi] = *(const bf16x8*)&Ag[m * 128 + chunk * 8];
        afH[mi] = *(const bf16x8*)&Hs[m * 128 + chunk * 8];
      }
      #pragma unroll
      for (int g = 0; g < 3; ++g)
        #pragma unroll
        for (int mi = 0; mi < 2; ++mi) {
          accI[mi][g] = __builtin_amdgcn_mfma_f32_16x16x32_bf16(afA[mi], BI[g][s], accI[mi][g], 0, 0, 0);
          accH[mi][g] = __builtin_amdgcn_mfma_f32_16x16x32_bf16(afH[mi], BH[g][s], accH[mi][g], 0, 0, 0);
        }
    }

    const int n0 = ci * 32;
    #pragma unroll
    for (int mi = 0; mi < 2; ++mi) {
      #pragma unroll
      for (int r = 0; r < 4; ++r) {
        int row = mi * 16 + quad * 4 + r;
        int n = n0 + row;
        if (n >= N) continue;
        float ir = accI[mi][0][r] + bir;
        float iz = accI[mi][1][r] + biz;
        float in_ = accI[mi][2][r] + bin_;
        float hr = accH[mi][0][r] + bhr;
        float hz = accH[mi][1][r] + bhz;
        float hn = accH[mi][2][r] + bhn;
        float rr = sigf(ir + hr);
        float zz = sigf(iz + hz);
        float nn = tanhfast(in_ + rr * hn);
        float hold = bf2f((unsigned int)Hs[row * 128 + ((c0 ^ (row & 15)) * 8) + ej]);
        hb[(size_t)n * 128 + jc] = f2bf_rne((1.f - zz) * nn + zz * hold);
      }
    }
    __syncthreads();
  }
}

// ---- one-block-per-graph mean pool (batch sorted; no atomics) ------------
__device__ __forceinline__ int lbound(const int* a, int n, int key) {
  int lo = 0, hi = n;
  while (lo < hi) {
    int mid = (lo + hi) >> 1;
    if (a[mid] < key) lo = mid + 1; else hi = mid;
  }
  return lo;
}

__global__ __launch_bounds__(512) void pool_kernel(
    const unsigned short* __restrict__ hb, const int* __restrict__ batch,
    float* __restrict__ out, int N) {
  __shared__ float red[32 * 128];  // 16 KB
  int g = blockIdx.x;
  int lo = lbound(batch, N, g);
  int hi = lbound(batch, N, g + 1);
  int t = threadIdx.x;
  int grp = t >> 4, lane = t & 15;
  float a[8] = {0.f, 0.f, 0.f, 0.f, 0.f, 0.f, 0.f, 0.f};
  for (int n = lo + grp; n < hi; n += 32) {
    uint4 v = *(const uint4*)&hb[(size_t)n * 128 + lane * 8];
    const unsigned int* dp = (const unsigned int*)&v;
    #pragma unroll
    for (int u = 0; u < 4; ++u) {
      a[2 * u]     += bf2f(dp[u] & 0xffffu);
      a[2 * u + 1] += bf2f(dp[u] >> 16);
    }
  }
  #pragma unroll
  for (int u = 0; u < 8; ++u) red[grp * 128 + lane * 8 + u] = a[u];
  __syncthreads();
  if (t < 128) {
    float s = 0.f;
    #pragma unroll
    for (int q = 0; q < 32; ++q) s += red[q * 128 + t];
    out[(size_t)g * 128 + t] = s / (float)max(hi - lo, 1);
  }
}

extern "C" void kernel_launch(void* const* d_in, const int* in_sizes, int n_in,
                              void* d_out, int out_size, void* d_ws, size_t ws_size,
                              hipStream_t stream) {
  const int* node_ids = (const int*)d_in[0];
  const int* edge_index = (const int*)d_in[1];
  const int* batch = (const int*)d_in[2];
  const float* embed = (const float*)d_in[4];
  const float* conv_w = (const float*)d_in[5];
  const float* w_ih = (const float*)d_in[6];
  const float* w_hh = (const float*)d_in[7];
  const float* b_ih = (const float*)d_in[8];
  const float* b_hh = (const float*)d_in[9];
  float* out = (float*)d_out;

  const int N = in_sizes[0];
  const int E = in_sizes[1] / 2;
  const int G = out_size / 128;
  const int NUM_LAYERS = in_sizes[5] / (128 * 128);

  const int* e_src = edge_index;
  const int* e_dst = edge_index + E;

  // ---- workspace carve-up (16B aligned) ----
  char* p = (char*)d_ws;
  unsigned short* hb = (unsigned short*)p;    p += (size_t)N * 128 * 2;
  unsigned short* aggb = (unsigned short*)p;  p += (size_t)N * 128 * 2;
  unsigned short* wpk_hh = (unsigned short*)p; p += (size_t)384 * 128 * 2;
  unsigned short* wpk_wc = (unsigned short*)p; p += (size_t)NUM_LAYERS * 384 * 128 * 2;
  int* deg = (int*)p;        p += (size_t)N * 4;
  int* csr = (int*)p;        p += (size_t)N * CAP * 4;

  // zero deg (graph-capture-safe memset node)
  hipMemsetAsync(deg, 0, (size_t)N * 4, stream);

  // fused setup: scatter blocks first (longest pole), then gather, then pack
  const int nS = (E + DTHREADS * 4 - 1) / (DTHREADS * 4);          // 782
  const int nG = (N * 32 + DTHREADS - 1) / DTHREADS;               // 6250
  const int nP = ((NUM_LAYERS + 1) * 384 * 128 + DTHREADS - 1) / DTHREADS;  // 577
  setup_kernel<<<nS + nG + nP, DTHREADS, 0, stream>>>(
      e_src, e_dst, deg, csr, E, nS,
      embed, node_ids, hb, N, nG,
      w_hh, conv_w, w_ih, wpk_hh, wpk_wc, NUM_LAYERS);

  const int nchunks = (N + 31) / 32;
  for (int L = 0; L < NUM_LAYERS; ++L) {
    aggregate_kernel<<<((size_t)N * 16 + DTHREADS - 1) / DTHREADS, DTHREADS, 0, stream>>>(
        hb, deg, csr, aggb, N);
    fused_gru_kernel<<<512, 512, 0, stream>>>(
        aggb, wpk_wc + (size_t)L * 384 * 128, wpk_hh, b_ih, b_hh, hb, N, nchunks);
  }

  pool_kernel<<<G, 512, 0, stream>>>(hb, batch, out, N);
}

// Round 7
// 286.458 us; speedup vs baseline: 1.1232x; 1.1232x over previous
//
#include <hip/hip_runtime.h>
#include <hip/hip_bf16.h>

// GatedConv: N=50000, E=800000, D=128, G=64, 2 layers.
// Round 16: revert the setup fusion (r15: co-running streaming gather with
// the atomic-RMW scatter stretched it 47->110us). Base = r14 (292us).
// One change: XCD-SLICED scatter. dst-space is split into 8 slices of
// N/8 nodes; block (bid&7)==s scans the full edge list but only commits
// edges whose dst is in slice s. Under the bid%8->XCD round-robin, each
// slice's csr region (1.6MB) + deg slice (25KB) are XCD-local and
// L2-resident: atomics/stores hit hot L2, each dirty line flushes once
// (was: every 4B store ping-ponged a 64B line across 8 XCDs -> 47MB
// write traffic). Edge list re-read 8x (coalesced, L3-served, cheap).
// Correct regardless of the XCD mapping (ownership from dst only).

#define DTHREADS 256
#define CAP 64

typedef __attribute__((ext_vector_type(8))) short bf16x8;
typedef __attribute__((ext_vector_type(4))) float f32x4;

__device__ __forceinline__ float sigf(float x) { return 1.0f / (1.0f + __expf(-x)); }
__device__ __forceinline__ float tanhfast(float x) { return 1.0f - 2.0f / (1.0f + __expf(2.0f * x)); }

__device__ __forceinline__ unsigned short f2bf_rne(float x) {
  unsigned int u = __float_as_uint(x);
  u += 0x7fff + ((u >> 16) & 1);
  return (unsigned short)(u >> 16);
}
__device__ __forceinline__ float bf2f(unsigned int lo16) {
  return __uint_as_float(lo16 << 16);
}

// ---- embed gather: hb[n,:] = bf16(embed[node_ids[n],:]) ------------------
__global__ __launch_bounds__(DTHREADS) void gather_kernel(
    const float* __restrict__ embed, const int* __restrict__ node_ids,
    unsigned short* __restrict__ hb, int N) {
  int idx = blockIdx.x * DTHREADS + threadIdx.x;
  if (idx >= N * 32) return;
  int n = idx >> 5;
  int c = (idx & 31) * 4;
  int v = node_ids[n];
  float4 val = *(const float4*)&embed[(size_t)v * 128 + c];
  unsigned short b[4] = {f2bf_rne(val.x), f2bf_rne(val.y), f2bf_rne(val.z), f2bf_rne(val.w)};
  *(ushort4*)&hb[(size_t)n * 128 + c] = *(ushort4*)b;
}

// ---- pack all weights + zero deg -----------------------------------------
__global__ __launch_bounds__(DTHREADS) void pack_all_kernel(
    const float* __restrict__ w_hh, const float* __restrict__ conv_w,
    const float* __restrict__ w_ih, unsigned short* __restrict__ wpk_hh,
    unsigned short* __restrict__ wpk_wc, int nl,
    int* __restrict__ deg, int N) {
  int id = blockIdx.x * DTHREADS + threadIdx.x;
  if (id < N) deg[id] = 0;
  int seg = id / (384 * 128);
  if (seg > nl) return;
  int r = id - seg * (384 * 128);
  int f = r >> 3, i = r & 7;
  int l = f & 63;
  int s = (f >> 6) & 3;
  int t = (f >> 8) & 3;
  int jb = f >> 10;
  int j = jb * 64 + t * 16 + (l & 15);
  int k = s * 32 + (l >> 4) * 8 + i;
  float val;
  unsigned short* dst;
  if (seg == 0) {
    val = w_hh[j * 128 + k];
    dst = wpk_hh;
  } else {
    const float* conv = conv_w + (size_t)(seg - 1) * 128 * 128;
    float acc = 0.f;
    for (int d = 0; d < 128; d += 4) {
      float4 cv = *(const float4*)&conv[k * 128 + d];
      float4 wv = *(const float4*)&w_ih[j * 128 + d];
      acc += cv.x * wv.x + cv.y * wv.y + cv.z * wv.z + cv.w * wv.w;
    }
    val = acc;
    dst = wpk_wc + (size_t)(seg - 1) * 384 * 128;
  }
  dst[(size_t)f * 8 + i] = f2bf_rne(val);
}

// ---- XCD-sliced scatter into padded per-node slots -----------------------
// slice s owns dst in [s*spn, (s+1)*spn); block (bid&7)==s scans all edges.
__global__ __launch_bounds__(DTHREADS) void scatter_sliced_kernel(
    const int* __restrict__ src, const int* __restrict__ dst,
    int* __restrict__ deg, int* __restrict__ csr, int E, int spn) {
  const int slice = blockIdx.x & 7;
  const int g = blockIdx.x >> 3;
  const int stride = (gridDim.x >> 3) * DTHREADS;
  const int lo = slice * spn, hi = lo + spn;
  for (int e = g * DTHREADS + threadIdx.x; e < E; e += stride) {
    int d = dst[e];
    if (d >= lo && d < hi) {
      int slot = atomicAdd(&deg[d], 1);
      if (slot < CAP) csr[(size_t)d * CAP + slot] = src[e];
    }
  }
}

// ---- aggregate: quarter-wave (16 lanes) per node, 16 edges in flight -----
__global__ __launch_bounds__(DTHREADS) void aggregate_kernel(
    const unsigned short* __restrict__ hb, const int* __restrict__ deg,
    const int* __restrict__ csr, unsigned short* __restrict__ agg, int N) {
  int node = (blockIdx.x * DTHREADS + threadIdx.x) >> 4;
  if (node >= N) return;
  int c = threadIdx.x & 15;
  int e = min(deg[node], CAP);
  const int* cs = csr + (size_t)node * CAP;
  float acc[8] = {0.f, 0.f, 0.f, 0.f, 0.f, 0.f, 0.f, 0.f};
  for (int i = 0; i < e; i += 16) {
    int idx[16];
    #pragma unroll
    for (int q = 0; q < 16; ++q) {
      int ii = i + q;
      idx[q] = cs[ii < e ? ii : 0];
    }
    uint4 d[16];
    #pragma unroll
    for (int q = 0; q < 16; ++q)
      d[q] = *(const uint4*)&hb[(size_t)idx[q] * 128 + c * 8];
    #pragma unroll
    for (int q = 0; q < 16; ++q) {
      if (i + q < e) {
        const unsigned int* dp = (const unsigned int*)&d[q];
        #pragma unroll
        for (int u = 0; u < 4; ++u) {
          acc[2 * u]     += bf2f(dp[u] & 0xffffu);
          acc[2 * u + 1] += bf2f(dp[u] >> 16);
        }
      }
    }
  }
  unsigned int o[4];
  #pragma unroll
  for (int q = 0; q < 4; ++q)
    o[q] = (unsigned int)f2bf_rne(acc[2 * q]) | ((unsigned int)f2bf_rne(acc[2 * q + 1]) << 16);
  *(uint4*)&agg[(size_t)node * 128 + c * 8] = *(uint4*)o;
}

// ---- persistent fused GRU (weights in VGPRs, register prefetch) ----------
__global__ __launch_bounds__(512, 2) void fused_gru_kernel(
    const unsigned short* __restrict__ aggb, const unsigned short* __restrict__ wpk_wc,
    const unsigned short* __restrict__ wpk_hh, const float* __restrict__ b_ih,
    const float* __restrict__ b_hh, unsigned short* __restrict__ hb,
    int N, int nchunks) {
  __shared__ __align__(16) unsigned short Ag[32 * 128];  // 8 KB
  __shared__ __align__(16) unsigned short Hs[32 * 128];  // 8 KB
  const int tid = threadIdx.x;
  const int wv = tid >> 6, lane = tid & 63;
  const int lm = lane & 15, quad = lane >> 4;

  bf16x8 BI[3][4], BH[3][4];
  #pragma unroll
  for (int g = 0; g < 3; ++g) {
    int jb = g * 2 + (wv >> 2);
    int t = wv & 3;
    #pragma unroll
    for (int s = 0; s < 4; ++s) {
      size_t f = ((size_t)(jb * 4 + t) * 4 + s) * 64 + lane;
      BI[g][s] = *(const bf16x8*)&wpk_wc[f * 8];
      BH[g][s] = *(const bf16x8*)&wpk_hh[f * 8];
    }
  }

  const int jc = wv * 16 + lm;
  const float bir = b_ih[jc], biz = b_ih[128 + jc], bin_ = b_ih[256 + jc];
  const float bhr = b_hh[jc], bhz = b_hh[128 + jc], bhn = b_hh[256 + jc];
  const int c0 = jc >> 3, ej = jc & 7;

  const int srow = tid >> 4, scol = tid & 15;
  const int sdc = (scol ^ (srow & 15)) * 8;

  int ci = blockIdx.x;
  uint4 va = make_uint4(0, 0, 0, 0), vh = make_uint4(0, 0, 0, 0);
  if (ci < nchunks) {
    int n = ci * 32 + srow;
    if (n < N) {
      va = *(const uint4*)&aggb[(size_t)n * 128 + scol * 8];
      vh = *(const uint4*)&hb[(size_t)n * 128 + scol * 8];
    }
  }

  for (; ci < nchunks; ci += gridDim.x) {
    *(uint4*)&Ag[srow * 128 + sdc] = va;
    *(uint4*)&Hs[srow * 128 + sdc] = vh;
    __syncthreads();

    int cn = ci + gridDim.x;
    va = make_uint4(0, 0, 0, 0); vh = make_uint4(0, 0, 0, 0);
    if (cn < nchunks) {
      int n = cn * 32 + srow;
      if (n < N) {
        va = *(const uint4*)&aggb[(size_t)n * 128 + scol * 8];
        vh = *(const uint4*)&hb[(size_t)n * 128 + scol * 8];
      }
    }

    f32x4 accI[2][3], accH[2][3];
    #pragma unroll
    for (int mi = 0; mi < 2; ++mi)
      #pragma unroll
      for (int g = 0; g < 3; ++g) {
        accI[mi][g] = (f32x4){0.f, 0.f, 0.f, 0.f};
        accH[mi][g] = (f32x4){0.f, 0.f, 0.f, 0.f};
      }

    #pragma unroll
    for (int s = 0; s < 4; ++s) {
      bf16x8 afA[2], afH[2];
      #pragma unroll
      for (int mi = 0; mi < 2; ++mi) {
        int m = mi * 16 + lm;
        int chunk = (s * 4 + quad) ^ (m & 15);
        afA[mi] = *(const bf16x8*)&Ag[m * 128 + chunk * 8];
        afH[mi] = *(const bf16x8*)&Hs[m * 128 + chunk * 8];
      }
      #pragma unroll
      for (int g = 0; g < 3; ++g)
        #pragma unroll
        for (int mi = 0; mi < 2; ++mi) {
          accI[mi][g] = __builtin_amdgcn_mfma_f32_16x16x32_bf16(afA[mi], BI[g][s], accI[mi][g], 0, 0, 0);
          accH[mi][g] = __builtin_amdgcn_mfma_f32_16x16x32_bf16(afH[mi], BH[g][s], accH[mi][g], 0, 0, 0);
        }
    }

    const int n0 = ci * 32;
    #pragma unroll
    for (int mi = 0; mi < 2; ++mi) {
      #pragma unroll
      for (int r = 0; r < 4; ++r) {
        int row = mi * 16 + quad * 4 + r;
        int n = n0 + row;
        if (n >= N) continue;
        float ir = accI[mi][0][r] + bir;
        float iz = accI[mi][1][r] + biz;
        float in_ = accI[mi][2][r] + bin_;
        float hr = accH[mi][0][r] + bhr;
        float hz = accH[mi][1][r] + bhz;
        float hn = accH[mi][2][r] + bhn;
        float rr = sigf(ir + hr);
        float zz = sigf(iz + hz);
        float nn = tanhfast(in_ + rr * hn);
        float hold = bf2f((unsigned int)Hs[row * 128 + ((c0 ^ (row & 15)) * 8) + ej]);
        hb[(size_t)n * 128 + jc] = f2bf_rne((1.f - zz) * nn + zz * hold);
      }
    }
    __syncthreads();
  }
}

// ---- one-block-per-graph mean pool (batch sorted; no atomics) ------------
__device__ __forceinline__ int lbound(const int* a, int n, int key) {
  int lo = 0, hi = n;
  while (lo < hi) {
    int mid = (lo + hi) >> 1;
    if (a[mid] < key) lo = mid + 1; else hi = mid;
  }
  return lo;
}

__global__ __launch_bounds__(512) void pool_kernel(
    const unsigned short* __restrict__ hb, const int* __restrict__ batch,
    float* __restrict__ out, int N) {
  __shared__ float red[32 * 128];  // 16 KB
  int g = blockIdx.x;
  int lo = lbound(batch, N, g);
  int hi = lbound(batch, N, g + 1);
  int t = threadIdx.x;
  int grp = t >> 4, lane = t & 15;
  float a[8] = {0.f, 0.f, 0.f, 0.f, 0.f, 0.f, 0.f, 0.f};
  for (int n = lo + grp; n < hi; n += 32) {
    uint4 v = *(const uint4*)&hb[(size_t)n * 128 + lane * 8];
    const unsigned int* dp = (const unsigned int*)&v;
    #pragma unroll
    for (int u = 0; u < 4; ++u) {
      a[2 * u]     += bf2f(dp[u] & 0xffffu);
      a[2 * u + 1] += bf2f(dp[u] >> 16);
    }
  }
  #pragma unroll
  for (int u = 0; u < 8; ++u) red[grp * 128 + lane * 8 + u] = a[u];
  __syncthreads();
  if (t < 128) {
    float s = 0.f;
    #pragma unroll
    for (int q = 0; q < 32; ++q) s += red[q * 128 + t];
    out[(size_t)g * 128 + t] = s / (float)max(hi - lo, 1);
  }
}

extern "C" void kernel_launch(void* const* d_in, const int* in_sizes, int n_in,
                              void* d_out, int out_size, void* d_ws, size_t ws_size,
                              hipStream_t stream) {
  const int* node_ids = (const int*)d_in[0];
  const int* edge_index = (const int*)d_in[1];
  const int* batch = (const int*)d_in[2];
  const float* embed = (const float*)d_in[4];
  const float* conv_w = (const float*)d_in[5];
  const float* w_ih = (const float*)d_in[6];
  const float* w_hh = (const float*)d_in[7];
  const float* b_ih = (const float*)d_in[8];
  const float* b_hh = (const float*)d_in[9];
  float* out = (float*)d_out;

  const int N = in_sizes[0];
  const int E = in_sizes[1] / 2;
  const int G = out_size / 128;
  const int NUM_LAYERS = in_sizes[5] / (128 * 128);

  const int* e_src = edge_index;
  const int* e_dst = edge_index + E;

  // ---- workspace carve-up (16B aligned) ----
  char* p = (char*)d_ws;
  unsigned short* hb = (unsigned short*)p;    p += (size_t)N * 128 * 2;
  unsigned short* aggb = (unsigned short*)p;  p += (size_t)N * 128 * 2;
  unsigned short* wpk_hh = (unsigned short*)p; p += (size_t)384 * 128 * 2;
  unsigned short* wpk_wc = (unsigned short*)p; p += (size_t)NUM_LAYERS * 384 * 128 * 2;
  int* deg = (int*)p;        p += (size_t)N * 4;
  int* csr = (int*)p;        p += (size_t)N * CAP * 4;

  // pack weights + zero deg (one dispatch)
  {
    int total = (NUM_LAYERS + 1) * 384 * 128;  // 147456 >= N
    pack_all_kernel<<<(total + DTHREADS - 1) / DTHREADS, DTHREADS, 0, stream>>>(
        w_hh, conv_w, w_ih, wpk_hh, wpk_wc, NUM_LAYERS, deg, N);
  }

  // XCD-sliced CSR build (one dispatch; reused by both layers)
  {
    const int spn = (N + 7) / 8;
    scatter_sliced_kernel<<<8 * 256, DTHREADS, 0, stream>>>(
        e_src, e_dst, deg, csr, E, spn);
  }

  gather_kernel<<<(N * 32 + DTHREADS - 1) / DTHREADS, DTHREADS, 0, stream>>>(embed, node_ids, hb, N);

  const int nchunks = (N + 31) / 32;
  for (int L = 0; L < NUM_LAYERS; ++L) {
    aggregate_kernel<<<((size_t)N * 16 + DTHREADS - 1) / DTHREADS, DTHREADS, 0, stream>>>(
        hb, deg, csr, aggb, N);
    fused_gru_kernel<<<512, 512, 0, stream>>>(
        aggb, wpk_wc + (size_t)L * 384 * 128, wpk_hh, b_ih, b_hh, hb, N, nchunks);
  }

  pool_kernel<<<G, 512, 0, stream>>>(hb, batch, out, N);
}